// Round 6
// baseline (13433.891 us; speedup 1.0000x reference)
//
#include <hip/hip_runtime.h>
#include <hip/hip_bf16.h>
#include <stdint.h>

#define T_STEPS 512
#define NBATCH 64
#define HID 1024
#define NGATE 4096
#define NLAYERS 2
#define TCHUNK 128
#define BH (NBATCH * HID)            // 65536
#define TBH (T_STEPS * NBATCH * HID) // 33554432
#define WEL ((size_t)NLAYERS * NGATE * HID)
#define NBLK 256

typedef __attribute__((ext_vector_type(8))) short short8;
typedef __attribute__((ext_vector_type(4))) float f32x4;

__device__ __forceinline__ ushort f2bf(float f) {
  union { float f; uint32_t i; } u; u.f = f;
  return (ushort)((u.i + 0x7fffu + ((u.i >> 16) & 1u)) >> 16);  // RNE
}
__device__ __forceinline__ float bf2f(ushort b) {
  union { uint32_t i; float f; } u; u.i = ((uint32_t)b) << 16;
  return u.f;
}
__device__ __forceinline__ void gll16(const void* g, void* l) {
  __builtin_amdgcn_global_load_lds(
      (const __attribute__((address_space(1))) unsigned int*)g,
      (__attribute__((address_space(3))) unsigned int*)l, 16, 0, 0);
}

// Cross-XCD-coherent h transport: compiler-generated agent-scope relaxed atomics
// (lower to cache-bypassing global loads, vmcnt-tracked, spill-safe). CRITICAL:
// loads are issued in batches of 8 fragments with NO consumer in between, so the
// waitcnt lands at first use and 16+ loads stay in flight (round 5 consumed each
// fragment immediately -> one exposed L3 round trip per fragment -> 17us/step).
union FragU { unsigned long long u[2]; short8 s8; };
__device__ __forceinline__ short8 ld_frag_sys(const ushort* p) {
  FragU r;
  r.u[0] = __hip_atomic_load((const unsigned long long*)p,       __ATOMIC_RELAXED, __HIP_MEMORY_SCOPE_AGENT);
  r.u[1] = __hip_atomic_load((const unsigned long long*)(p + 4), __ATOMIC_RELAXED, __HIP_MEMORY_SCOPE_AGENT);
  return r.s8;
}
__device__ __forceinline__ void ldb8(short8* dst, const ushort* base) {
#pragma unroll
  for (int q = 0; q < 8; ++q) dst[q] = ld_frag_sys(base + q * 32);
}
__device__ __forceinline__ void cons8(const short8* src, const char* bb0, const char* bb1,
                                      int kcBase, int kb, int bsw, f32x4& accA, f32x4& accB) {
#pragma unroll
  for (int q = 0; q < 8; ++q) {
    const int kc = kcBase + q;
    short8 b0v = *(const short8*)(bb0 + ((kc * 64 + kb) ^ bsw));
    short8 b1v = *(const short8*)(bb1 + ((kc * 64 + kb) ^ bsw));
    accA = __builtin_amdgcn_mfma_f32_16x16x32_bf16(src[q], b0v, accA, 0, 0, 0);
    accB = __builtin_amdgcn_mfma_f32_16x16x32_bf16(src[q], b1v, accB, 0, 0, 0);
  }
}

// ---------------- elementwise helpers ----------------
__global__ void k_f32_to_bf16(const float* __restrict__ in, ushort* __restrict__ out, int n) {
  int i = (blockIdx.x * blockDim.x + threadIdx.x) * 4;
  if (i >= n) return;
  const float4 v = *reinterpret_cast<const float4*>(in + i);
  ushort4 o; o.x = f2bf(v.x); o.y = f2bf(v.y); o.z = f2bf(v.z); o.w = f2bf(v.w);
  *reinterpret_cast<ushort4*>(out + i) = o;
}
__global__ void k_copy_f32(const float* __restrict__ in, float* __restrict__ out, int n) {
  int i = (blockIdx.x * blockDim.x + threadIdx.x) * 4;
  if (i >= n) return;
  *reinterpret_cast<float4*>(out + i) = *reinterpret_cast<const float4*>(in + i);
}
__global__ void k_zero(int* p, int n) {
  int i = blockIdx.x * blockDim.x + threadIdx.x;
  if (i < n) p[i] = 0;
}

// ---------------- igates GEMM (layer 0 only): C(8192,4096) = A @ W_ih0^T + b ----------------
__global__ __launch_bounds__(256) void k_gemm_ig(
    const ushort* __restrict__ A, const ushort* __restrict__ W,
    const float* __restrict__ bia, const float* __restrict__ bib,
    ushort* __restrict__ C)
{
  __shared__ __align__(16) ushort At[128 * 64];
  __shared__ __align__(16) ushort Bt[128 * 64];
  const int tid = threadIdx.x;
  const int wave = tid >> 6, lane = tid & 63;
  const int m0 = blockIdx.x * 128;
  const int n0 = blockIdx.y * 128;
  const int wr = wave >> 1, wc = wave & 1;

  const int r_st = wave * 8 + (lane >> 3);
  const int bsw = ((lane & 7) * 16) ^ ((r_st & 7) << 4);
  const ushort* aSrc = A + (size_t)(m0 + r_st) * 1024 + (bsw >> 1);
  const ushort* bSrc = W + (size_t)(n0 + r_st) * 1024 + (bsw >> 1);
  ushort* aDst = At + wave * 512;
  ushort* bDst = Bt + wave * 512;

  f32x4 acc[4][4];
#pragma unroll
  for (int a = 0; a < 4; ++a)
#pragma unroll
    for (int b = 0; b < 4; ++b) acc[a][b] = (f32x4){0.f, 0.f, 0.f, 0.f};

  for (int ks = 0; ks < 16; ++ks) {
#pragma unroll
    for (int i = 0; i < 4; ++i) {
      gll16(aSrc + (size_t)i * 32 * 1024 + ks * 64, aDst + i * 2048);
      gll16(bSrc + (size_t)i * 32 * 1024 + ks * 64, bDst + i * 2048);
    }
    __syncthreads();
#pragma unroll
    for (int kc = 0; kc < 2; ++kc) {
      const int kb = kc * 64 + (lane >> 4) * 16;
      short8 af[4], bfr[4];
#pragma unroll
      for (int mt = 0; mt < 4; ++mt) {
        const int r = wr * 64 + mt * 16 + (lane & 15);
        af[mt] = *(const short8*)((const char*)At + r * 128 + (kb ^ ((r & 7) << 4)));
      }
#pragma unroll
      for (int nt = 0; nt < 4; ++nt) {
        const int r = wc * 64 + nt * 16 + (lane & 15);
        bfr[nt] = *(const short8*)((const char*)Bt + r * 128 + (kb ^ ((r & 7) << 4)));
      }
#pragma unroll
      for (int mt = 0; mt < 4; ++mt)
#pragma unroll
        for (int nt = 0; nt < 4; ++nt)
          acc[mt][nt] = __builtin_amdgcn_mfma_f32_16x16x32_bf16(af[mt], bfr[nt], acc[mt][nt], 0, 0, 0);
    }
    __syncthreads();
  }

#pragma unroll
  for (int nt = 0; nt < 4; ++nt) {
    const int col = n0 + wc * 64 + nt * 16 + (lane & 15);
    const float bias = bia[col] + bib[col];
#pragma unroll
    for (int mt = 0; mt < 4; ++mt) {
      const int row = m0 + wr * 64 + mt * 16 + (lane >> 4) * 4;
      const f32x4 v = acc[mt][nt];
#pragma unroll
      for (int r = 0; r < 4; ++r)
        C[(size_t)(row + r) * 4096 + col] = f2bf(v[r] + bias);
    }
  }
}

// ---------------- persistent pipelined scan ----------------
struct ScanP {
  const ushort* wih1; const ushort* whh0; const ushort* whh1;
  const ushort* ig;   const ushort* hinit;
  ushort* h0r; ushort* h1r; float* cbuf;
  const float* bi1; const float* bh1;
  float* out; int* bar; int s0; int s1;
};

// Monotonic barrier, 4 stripes (relaxed-only, no resets). Poll = 4 consecutive
// atomic loads (pipelined, ~1 L3 round trip per poll round) + sum.
__device__ __forceinline__ void gbar(int* bar, int phase, int stripe) {
  __syncthreads();
  if (threadIdx.x == 0) {
    __hip_atomic_fetch_add(bar + stripe * 16, 1, __ATOMIC_RELAXED, __HIP_MEMORY_SCOPE_AGENT);
    const int target = (phase + 1) * NBLK;
    for (;;) {
      int v0 = __hip_atomic_load(bar,      __ATOMIC_RELAXED, __HIP_MEMORY_SCOPE_AGENT);
      int v1 = __hip_atomic_load(bar + 16, __ATOMIC_RELAXED, __HIP_MEMORY_SCOPE_AGENT);
      int v2 = __hip_atomic_load(bar + 32, __ATOMIC_RELAXED, __HIP_MEMORY_SCOPE_AGENT);
      int v3 = __hip_atomic_load(bar + 48, __ATOMIC_RELAXED, __HIP_MEMORY_SCOPE_AGENT);
      if (v0 + v1 + v2 + v3 >= target) break;
      __builtin_amdgcn_s_sleep(2);
    }
  }
  __syncthreads();
  __builtin_amdgcn_sched_barrier(0);
}

// 256 blocks x 256 threads. Blocks 0..127: layer0 step s. Blocks 128..255: layer1 step s-1
// (K=2048 fused [W_ih1|W_hh1], A = [h0_{s-1} ; h1_{s-2}]). W staged once in LDS.
__global__ __launch_bounds__(256, 1) void k_scan(ScanP p) {
  __shared__ __align__(16) ushort Wl[32 * 2048];  // 128 KB
  __shared__ float glds[64 * 33];
  const int tid = threadIdx.x, wave = tid >> 6, lane = tid & 63;
  const bool isL1 = blockIdx.x >= 128;
  const int cb = isL1 ? (int)blockIdx.x - 128 : (int)blockIdx.x;
  const int j0 = cb * 8;
  const int stripe = blockIdx.x & 3;

  if (isL1) {
    for (int q = wave; q < 128; q += 4) {
      const int i = q >> 2, ch = q & 3;
      const ushort* base = (ch < 2) ? p.wih1 : p.whh1;
      const int g = (i >> 3) * 1024 + j0 + (i & 7);
      gll16(base + (size_t)g * 1024 + (ch & 1) * 512 + (((lane * 16) ^ ((i & 7) << 4)) >> 1),
            (char*)Wl + i * 4096 + ch * 1024);
    }
  } else {
    for (int q = wave; q < 64; q += 4) {
      const int i = q >> 1, ch = q & 1;
      const int g = (i >> 3) * 1024 + j0 + (i & 7);
      gll16(p.whh0 + (size_t)g * 1024 + ch * 512 + (((lane * 16) ^ ((i & 7) << 4)) >> 1),
            (char*)Wl + i * 4096 + ch * 1024);
    }
  }

  // Epilogue geometry: thread owns (b = tid>>2, j = j0 + (tid&3)*2 + {0,1})
  const int eb  = tid >> 2;
  const int jl0 = (tid & 3) * 2;
  const int jj  = j0 + jl0;
  float* cb_ = p.cbuf + (isL1 ? BH : 0);
  float creg[2], bias[4][2];
#pragma unroll
  for (int i = 0; i < 2; ++i) creg[i] = cb_[eb * 1024 + jj + i];
  if (isL1) {
#pragma unroll
    for (int g = 0; g < 4; ++g)
#pragma unroll
      for (int i = 0; i < 2; ++i)
        bias[g][i] = p.bi1[g * 1024 + jj + i] + p.bh1[g * 1024 + jj + i];
  }

  const size_t aoff = (size_t)(wave * 16 + (lane & 15)) * 1024 + (size_t)((lane >> 4) * 8);
  const int r0 = lane & 15;
  const char* bb0 = (const char*)Wl + r0 * 4096;
  const char* bb1 = (const char*)Wl + (r0 + 16) * 4096;
  const int bsw = (r0 & 7) << 4;
  const int kb = (lane >> 4) * 16;

  __syncthreads();  // W staged (vmcnt drained)

  for (int s = p.s0; s < p.s1; ++s) {
    const bool act = isL1 ? (s >= 1) : (s < T_STEPS);
    if (act) {
      f32x4 accA = {0.f, 0.f, 0.f, 0.f}, accB = {0.f, 0.f, 0.f, 0.f};
      short8 A0[8], A1[8];
      if (!isL1) {
        const ushort* h = ((s == 0) ? p.hinit : p.h0r + (size_t)((s - 1) & 1) * BH) + aoff;
        ldb8(A0, h);
        ldb8(A1, h + 256);
        cons8(A0, bb0, bb1, 0,  kb, bsw, accA, accB);
        ldb8(A0, h + 512);
        cons8(A1, bb0, bb1, 8,  kb, bsw, accA, accB);
        ldb8(A1, h + 768);
        cons8(A0, bb0, bb1, 16, kb, bsw, accA, accB);
        cons8(A1, bb0, bb1, 24, kb, bsw, accA, accB);
      } else {
        const ushort* h0p = p.h0r + (size_t)((s - 1) & 1) * BH + aoff;
        const ushort* h1p = ((s == 1) ? p.hinit + BH : p.h1r + (size_t)(s & 1) * BH) + aoff;
        ldb8(A0, h0p);
        ldb8(A1, h0p + 256);
        cons8(A0, bb0, bb1, 0,  kb, bsw, accA, accB);
        ldb8(A0, h0p + 512);
        cons8(A1, bb0, bb1, 8,  kb, bsw, accA, accB);
        ldb8(A1, h0p + 768);
        cons8(A0, bb0, bb1, 16, kb, bsw, accA, accB);
        ldb8(A0, h1p);
        cons8(A1, bb0, bb1, 24, kb, bsw, accA, accB);
        ldb8(A1, h1p + 256);
        cons8(A0, bb0, bb1, 32, kb, bsw, accA, accB);
        ldb8(A0, h1p + 512);
        cons8(A1, bb0, bb1, 40, kb, bsw, accA, accB);
        ldb8(A1, h1p + 768);
        cons8(A0, bb0, bb1, 48, kb, bsw, accA, accB);
        cons8(A1, bb0, bb1, 56, kb, bsw, accA, accB);
      }
#pragma unroll
      for (int r = 0; r < 4; ++r) {
        const int row = wave * 16 + (lane >> 4) * 4 + r;
        glds[row * 33 + r0]      = accA[r];
        glds[row * 33 + 16 + r0] = accB[r];
      }
      __syncthreads();

      const ushort* ig_ = p.ig + (size_t)(s & (TCHUNK - 1)) * (NBATCH * NGATE);
      float hres[2];
#pragma unroll
      for (int i = 0; i < 2; ++i) {
        const int jl = jl0 + i;
        float gi, gf, gg, go;
        if (!isL1) {
          gi = glds[eb * 33 + jl]      + bf2f(ig_[eb * 4096 + jj + i]);
          gf = glds[eb * 33 + 8 + jl]  + bf2f(ig_[eb * 4096 + 1024 + jj + i]);
          gg = glds[eb * 33 + 16 + jl] + bf2f(ig_[eb * 4096 + 2048 + jj + i]);
          go = glds[eb * 33 + 24 + jl] + bf2f(ig_[eb * 4096 + 3072 + jj + i]);
        } else {
          gi = glds[eb * 33 + jl]      + bias[0][i];
          gf = glds[eb * 33 + 8 + jl]  + bias[1][i];
          gg = glds[eb * 33 + 16 + jl] + bias[2][i];
          go = glds[eb * 33 + 24 + jl] + bias[3][i];
        }
        float c = creg[i];
        const float si = 1.f / (1.f + __expf(-gi));
        const float sf = 1.f / (1.f + __expf(-gf));
        const float so = 1.f / (1.f + __expf(-go));
        const float tg = tanhf(gg);
        c = sf * c + si * tg;
        hres[i] = so * tanhf(c);
        creg[i] = c;
      }

      const uint32_t packed = (uint32_t)f2bf(hres[0]) | ((uint32_t)f2bf(hres[1]) << 16);
      ushort* hdst = (!isL1) ? (p.h0r + (size_t)(s & 1) * BH)
                             : (p.h1r + (size_t)((s - 1) & 1) * BH);
      uint32_t* hw = (uint32_t*)(hdst + eb * 1024 + jj);
      __hip_atomic_store(hw, packed, __ATOMIC_RELAXED, __HIP_MEMORY_SCOPE_AGENT);
      // Same-address load-back: when this returns, the store is committed at the
      // coherence point (per-address FIFO). Kept live via empty asm.
      uint32_t chk = __hip_atomic_load(hw, __ATOMIC_RELAXED, __HIP_MEMORY_SCOPE_AGENT);
      asm volatile("" :: "v"(chk));

      if (isL1) {
#pragma unroll
        for (int i = 0; i < 2; ++i)
          p.out[(size_t)(s - 1) * BH + eb * 1024 + jj + i] = hres[i];
        if (s - 1 == T_STEPS - 1) {
#pragma unroll
          for (int i = 0; i < 2; ++i) {
            p.out[(size_t)TBH + BH + eb * 1024 + jj + i] = hres[i];
            p.out[(size_t)TBH + 3 * BH + eb * 1024 + jj + i] = creg[i];
          }
        }
      } else if (s == T_STEPS - 1) {
#pragma unroll
        for (int i = 0; i < 2; ++i) {
          p.out[(size_t)TBH + eb * 1024 + jj + i] = hres[i];
          p.out[(size_t)TBH + 2 * BH + eb * 1024 + jj + i] = creg[i];
        }
      }
    }
    gbar(p.bar, s - p.s0, stripe);
  }
#pragma unroll
  for (int i = 0; i < 2; ++i) cb_[eb * 1024 + jj + i] = creg[i];
}

// ---------------- host ----------------
extern "C" void kernel_launch(void* const* d_in, const int* in_sizes, int n_in,
                              void* d_out, int out_size, void* d_ws, size_t ws_size,
                              hipStream_t stream) {
  const float* x    = (const float*)d_in[0];
  const float* h0   = (const float*)d_in[1];
  const float* c0   = (const float*)d_in[2];
  const float* w_ih = (const float*)d_in[3];
  const float* w_hh = (const float*)d_in[4];
  const float* b_ih = (const float*)d_in[5];
  const float* b_hh = (const float*)d_in[6];
  float* out = (float*)d_out;

  ushort* xb    = (ushort*)d_ws;
  ushort* wihb  = xb + (size_t)TBH;
  ushort* whhb  = wihb + WEL;
  ushort* ig    = whhb + WEL;
  ushort* hinit = ig + (size_t)TCHUNK * NBATCH * NGATE;
  ushort* h0r   = hinit + 2 * (size_t)BH;
  ushort* h1r   = h0r + 2 * (size_t)BH;
  float*  cbuf  = (float*)(h1r + 2 * (size_t)BH);
  int*    bar   = (int*)(cbuf + 2 * (size_t)BH);

  const size_t need = ((size_t)TBH + 2 * WEL + (size_t)TCHUNK * NBATCH * NGATE
                       + 6 * (size_t)BH) * 2 + 2 * (size_t)BH * 4 + 1024;
  if (ws_size < need) return;  // loud failure: d_out stays poisoned

  { int n = TBH;          k_f32_to_bf16<<<(n / 4 + 255) / 256, 256, 0, stream>>>(x, xb, n); }
  { int n = (int)WEL;     k_f32_to_bf16<<<(n / 4 + 255) / 256, 256, 0, stream>>>(w_ih, wihb, n); }
  { int n = (int)WEL;     k_f32_to_bf16<<<(n / 4 + 255) / 256, 256, 0, stream>>>(w_hh, whhb, n); }
  { int n = 2 * BH;       k_f32_to_bf16<<<(n / 4 + 255) / 256, 256, 0, stream>>>(h0, hinit, n); }
  k_copy_f32<<<(2 * BH / 4 + 255) / 256, 256, 0, stream>>>(c0, cbuf, 2 * BH);

  ScanP sp;
  sp.wih1 = wihb + (size_t)NGATE * HID;
  sp.whh0 = whhb;
  sp.whh1 = whhb + (size_t)NGATE * HID;
  sp.ig = ig; sp.hinit = hinit;
  sp.h0r = h0r; sp.h1r = h1r; sp.cbuf = cbuf;
  sp.bi1 = b_ih + NGATE; sp.bh1 = b_hh + NGATE;
  sp.out = out; sp.bar = bar;

  const int bounds[5] = {0, 128, 256, 384, 513};
  for (int c = 0; c < 4; ++c) {
    k_zero<<<1, 256, 0, stream>>>(bar, 256);
    k_gemm_ig<<<dim3(64, 32), 256, 0, stream>>>(
        xb + (size_t)c * TCHUNK * NBATCH * HID, wihb, b_ih, b_hh, ig);
    sp.s0 = bounds[c]; sp.s1 = bounds[c + 1];
    void* kp[1] = {&sp};
    hipLaunchCooperativeKernel(reinterpret_cast<void*>(&k_scan),
                               dim3(NBLK), dim3(256), kp, 0, stream);
  }
}

// Round 7
// 8803.516 us; speedup vs baseline: 1.5260x; 1.5260x over previous
//
#include <hip/hip_runtime.h>
#include <hip/hip_bf16.h>
#include <stdint.h>

#define T_STEPS 512
#define NBATCH 64
#define HID 1024
#define NGATE 4096
#define NLAYERS 2
#define TCHUNK 128
#define BH (NBATCH * HID)            // 65536
#define TBH (T_STEPS * NBATCH * HID) // 33554432
#define WEL ((size_t)NLAYERS * NGATE * HID)
#define NBLK 256

typedef __attribute__((ext_vector_type(8))) short short8;
typedef __attribute__((ext_vector_type(4))) float f32x4;

__device__ __forceinline__ ushort f2bf(float f) {
  union { float f; uint32_t i; } u; u.f = f;
  return (ushort)((u.i + 0x7fffu + ((u.i >> 16) & 1u)) >> 16);  // RNE
}
__device__ __forceinline__ float bf2f(ushort b) {
  union { uint32_t i; float f; } u; u.i = ((uint32_t)b) << 16;
  return u.f;
}
__device__ __forceinline__ void gll16(const void* g, void* l) {
  __builtin_amdgcn_global_load_lds(
      (const __attribute__((address_space(1))) unsigned int*)g,
      (__attribute__((address_space(3))) unsigned int*)l, 16, 0, 0);
}

// ---- hand-rolled h-load pipeline (cross-XCD coherent sc0 sc1 loads) ----
// 16 rotating slots (64 VGPRs; total pressure ~196 < 256 arch cap -> no spill,
// the round-3/round-6 failure mechanism). Counted vmcnt per consume; the wait
// asm ties the slot register through it ("+v") so the MFMA data-depends on the
// WAIT -- it can never be scheduled above it. vmcnt returns are in issue order,
// so foreign VMEM interleaved by the compiler only makes waits stronger.
#define ISS(SLOT, PTR, OFF) \
  asm volatile("global_load_dwordx4 %0, %1, off offset:" #OFF " sc0 sc1" \
               : "=v"(fr[SLOT]) : "v"(PTR));
#define VMW(N, SLOT) \
  asm volatile("s_waitcnt vmcnt(" #N ")" : "+v"(fr[SLOT]));
#define CON(SLOT, KC) { \
    const short8 b0v = *(const short8*)(bb0 + ((((KC) * 64) + kb) ^ bsw)); \
    const short8 b1v = *(const short8*)(bb1 + ((((KC) * 64) + kb) ^ bsw)); \
    accA = __builtin_amdgcn_mfma_f32_16x16x32_bf16(fr[SLOT], b0v, accA, 0, 0, 0); \
    accB = __builtin_amdgcn_mfma_f32_16x16x32_bf16(fr[SLOT], b1v, accB, 0, 0, 0); }

// ---------------- elementwise helpers ----------------
__global__ void k_f32_to_bf16(const float* __restrict__ in, ushort* __restrict__ out, int n) {
  int i = (blockIdx.x * blockDim.x + threadIdx.x) * 4;
  if (i >= n) return;
  const float4 v = *reinterpret_cast<const float4*>(in + i);
  ushort4 o; o.x = f2bf(v.x); o.y = f2bf(v.y); o.z = f2bf(v.z); o.w = f2bf(v.w);
  *reinterpret_cast<ushort4*>(out + i) = o;
}
__global__ void k_copy_f32(const float* __restrict__ in, float* __restrict__ out, int n) {
  int i = (blockIdx.x * blockDim.x + threadIdx.x) * 4;
  if (i >= n) return;
  *reinterpret_cast<float4*>(out + i) = *reinterpret_cast<const float4*>(in + i);
}
__global__ void k_zero(int* p, int n) {
  int i = blockIdx.x * blockDim.x + threadIdx.x;
  if (i < n) p[i] = 0;
}

// ---------------- igates GEMM (layer 0 only): C(8192,4096) = A @ W_ih0^T + b ----------------
__global__ __launch_bounds__(256) void k_gemm_ig(
    const ushort* __restrict__ A, const ushort* __restrict__ W,
    const float* __restrict__ bia, const float* __restrict__ bib,
    ushort* __restrict__ C)
{
  __shared__ __align__(16) ushort At[128 * 64];
  __shared__ __align__(16) ushort Bt[128 * 64];
  const int tid = threadIdx.x;
  const int wave = tid >> 6, lane = tid & 63;
  const int m0 = blockIdx.x * 128;
  const int n0 = blockIdx.y * 128;
  const int wr = wave >> 1, wc = wave & 1;

  const int r_st = wave * 8 + (lane >> 3);
  const int bsw = ((lane & 7) * 16) ^ ((r_st & 7) << 4);
  const ushort* aSrc = A + (size_t)(m0 + r_st) * 1024 + (bsw >> 1);
  const ushort* bSrc = W + (size_t)(n0 + r_st) * 1024 + (bsw >> 1);
  ushort* aDst = At + wave * 512;
  ushort* bDst = Bt + wave * 512;

  f32x4 acc[4][4];
#pragma unroll
  for (int a = 0; a < 4; ++a)
#pragma unroll
    for (int b = 0; b < 4; ++b) acc[a][b] = (f32x4){0.f, 0.f, 0.f, 0.f};

  for (int ks = 0; ks < 16; ++ks) {
#pragma unroll
    for (int i = 0; i < 4; ++i) {
      gll16(aSrc + (size_t)i * 32 * 1024 + ks * 64, aDst + i * 2048);
      gll16(bSrc + (size_t)i * 32 * 1024 + ks * 64, bDst + i * 2048);
    }
    __syncthreads();
#pragma unroll
    for (int kc = 0; kc < 2; ++kc) {
      const int kb = kc * 64 + (lane >> 4) * 16;
      short8 af[4], bfr[4];
#pragma unroll
      for (int mt = 0; mt < 4; ++mt) {
        const int r = wr * 64 + mt * 16 + (lane & 15);
        af[mt] = *(const short8*)((const char*)At + r * 128 + (kb ^ ((r & 7) << 4)));
      }
#pragma unroll
      for (int nt = 0; nt < 4; ++nt) {
        const int r = wc * 64 + nt * 16 + (lane & 15);
        bfr[nt] = *(const short8*)((const char*)Bt + r * 128 + (kb ^ ((r & 7) << 4)));
      }
#pragma unroll
      for (int mt = 0; mt < 4; ++mt)
#pragma unroll
        for (int nt = 0; nt < 4; ++nt)
          acc[mt][nt] = __builtin_amdgcn_mfma_f32_16x16x32_bf16(af[mt], bfr[nt], acc[mt][nt], 0, 0, 0);
    }
    __syncthreads();
  }

#pragma unroll
  for (int nt = 0; nt < 4; ++nt) {
    const int col = n0 + wc * 64 + nt * 16 + (lane & 15);
    const float bias = bia[col] + bib[col];
#pragma unroll
    for (int mt = 0; mt < 4; ++mt) {
      const int row = m0 + wr * 64 + mt * 16 + (lane >> 4) * 4;
      const f32x4 v = acc[mt][nt];
#pragma unroll
      for (int r = 0; r < 4; ++r)
        C[(size_t)(row + r) * 4096 + col] = f2bf(v[r] + bias);
    }
  }
}

// ---------------- persistent pipelined scan ----------------
struct ScanP {
  const ushort* wih1; const ushort* whh0; const ushort* whh1;
  const ushort* ig;   const ushort* hinit;
  ushort* h0r; ushort* h1r; float* cbuf;
  const float* bi1; const float* bh1;
  float* out; int* bar; int s0; int s1;
};

// Monotonic barrier, 4 stripes (relaxed-only, no resets).
__device__ __forceinline__ void gbar(int* bar, int phase, int stripe) {
  __syncthreads();
  if (threadIdx.x == 0) {
    __hip_atomic_fetch_add(bar + stripe * 16, 1, __ATOMIC_RELAXED, __HIP_MEMORY_SCOPE_AGENT);
    const int target = (phase + 1) * NBLK;
    for (;;) {
      int v0 = __hip_atomic_load(bar,      __ATOMIC_RELAXED, __HIP_MEMORY_SCOPE_AGENT);
      int v1 = __hip_atomic_load(bar + 16, __ATOMIC_RELAXED, __HIP_MEMORY_SCOPE_AGENT);
      int v2 = __hip_atomic_load(bar + 32, __ATOMIC_RELAXED, __HIP_MEMORY_SCOPE_AGENT);
      int v3 = __hip_atomic_load(bar + 48, __ATOMIC_RELAXED, __HIP_MEMORY_SCOPE_AGENT);
      if (v0 + v1 + v2 + v3 >= target) break;
      __builtin_amdgcn_s_sleep(2);
    }
  }
  __syncthreads();
  __builtin_amdgcn_sched_barrier(0);
}

// 256 blocks x 256 threads. Blocks 0..127: layer0 step s. Blocks 128..255: layer1 step s-1
// (K=2048 fused [W_ih1|W_hh1], A = [h0_{s-1} ; h1_{s-2}]). W staged once in LDS.
__global__ __launch_bounds__(256, 1) void k_scan(ScanP p) {
  __shared__ __align__(16) ushort Wl[32 * 2048];  // 128 KB
  __shared__ float glds[64 * 33];
  const int tid = threadIdx.x, wave = tid >> 6, lane = tid & 63;
  const bool isL1 = blockIdx.x >= 128;
  const int cb = isL1 ? (int)blockIdx.x - 128 : (int)blockIdx.x;
  const int j0 = cb * 8;
  const int stripe = blockIdx.x & 3;

  if (isL1) {
    for (int q = wave; q < 128; q += 4) {
      const int i = q >> 2, ch = q & 3;
      const ushort* base = (ch < 2) ? p.wih1 : p.whh1;
      const int g = (i >> 3) * 1024 + j0 + (i & 7);
      gll16(base + (size_t)g * 1024 + (ch & 1) * 512 + (((lane * 16) ^ ((i & 7) << 4)) >> 1),
            (char*)Wl + i * 4096 + ch * 1024);
    }
  } else {
    for (int q = wave; q < 64; q += 4) {
      const int i = q >> 1, ch = q & 1;
      const int g = (i >> 3) * 1024 + j0 + (i & 7);
      gll16(p.whh0 + (size_t)g * 1024 + ch * 512 + (((lane * 16) ^ ((i & 7) << 4)) >> 1),
            (char*)Wl + i * 4096 + ch * 1024);
    }
  }

  // Epilogue geometry: thread owns (b = tid>>2, j = j0 + (tid&3)*2 + {0,1})
  const int eb  = tid >> 2;
  const int jl0 = (tid & 3) * 2;
  const int jj  = j0 + jl0;
  float* cb_ = p.cbuf + (isL1 ? BH : 0);
  float creg[2], bias[4][2];
#pragma unroll
  for (int i = 0; i < 2; ++i) creg[i] = cb_[eb * 1024 + jj + i];
  if (isL1) {
#pragma unroll
    for (int g = 0; g < 4; ++g)
#pragma unroll
      for (int i = 0; i < 2; ++i)
        bias[g][i] = p.bi1[g * 1024 + jj + i] + p.bh1[g * 1024 + jj + i];
  }

  const size_t aoff = (size_t)(wave * 16 + (lane & 15)) * 1024 + (size_t)((lane >> 4) * 8);
  const int r0 = lane & 15;
  const char* bb0 = (const char*)Wl + r0 * 4096;
  const char* bb1 = (const char*)Wl + (r0 + 16) * 4096;
  const int bsw = (r0 & 7) << 4;
  const int kb = (lane >> 4) * 16;

  __syncthreads();  // W staged (vmcnt drained)

  for (int s = p.s0; s < p.s1; ++s) {
    const bool act = isL1 ? (s >= 1) : (s < T_STEPS);
    if (act) {
      f32x4 accA = {0.f, 0.f, 0.f, 0.f}, accB = {0.f, 0.f, 0.f, 0.f};
      short8 fr[16];
      if (!isL1) {
        const ushort* hp = (((s == 0) ? p.hinit : p.h0r + (size_t)((s - 1) & 1) * BH)) + aoff;
        ISS(0,hp,0)    ISS(1,hp,64)   ISS(2,hp,128)  ISS(3,hp,192)
        ISS(4,hp,256)  ISS(5,hp,320)  ISS(6,hp,384)  ISS(7,hp,448)
        ISS(8,hp,512)  ISS(9,hp,576)  ISS(10,hp,640) ISS(11,hp,704)
        ISS(12,hp,768) ISS(13,hp,832) ISS(14,hp,896) ISS(15,hp,960)
        VMW(15,0)  CON(0,0)   ISS(0,hp,1024)
        VMW(15,1)  CON(1,1)   ISS(1,hp,1088)
        VMW(15,2)  CON(2,2)   ISS(2,hp,1152)
        VMW(15,3)  CON(3,3)   ISS(3,hp,1216)
        VMW(15,4)  CON(4,4)   ISS(4,hp,1280)
        VMW(15,5)  CON(5,5)   ISS(5,hp,1344)
        VMW(15,6)  CON(6,6)   ISS(6,hp,1408)
        VMW(15,7)  CON(7,7)   ISS(7,hp,1472)
        VMW(15,8)  CON(8,8)   ISS(8,hp,1536)
        VMW(15,9)  CON(9,9)   ISS(9,hp,1600)
        VMW(15,10) CON(10,10) ISS(10,hp,1664)
        VMW(15,11) CON(11,11) ISS(11,hp,1728)
        VMW(15,12) CON(12,12) ISS(12,hp,1792)
        VMW(15,13) CON(13,13) ISS(13,hp,1856)
        VMW(15,14) CON(14,14) ISS(14,hp,1920)
        VMW(15,15) CON(15,15) ISS(15,hp,1984)
        VMW(15,0)  CON(0,16)
        VMW(14,1)  CON(1,17)
        VMW(13,2)  CON(2,18)
        VMW(12,3)  CON(3,19)
        VMW(11,4)  CON(4,20)
        VMW(10,5)  CON(5,21)
        VMW(9,6)   CON(6,22)
        VMW(8,7)   CON(7,23)
        VMW(7,8)   CON(8,24)
        VMW(6,9)   CON(9,25)
        VMW(5,10)  CON(10,26)
        VMW(4,11)  CON(11,27)
        VMW(3,12)  CON(12,28)
        VMW(2,13)  CON(13,29)
        VMW(1,14)  CON(14,30)
        VMW(0,15)  CON(15,31)
      } else {
        const ushort* h0p = p.h0r + (size_t)((s - 1) & 1) * BH + aoff;
        const ushort* h1p = ((s == 1) ? p.hinit + BH : p.h1r + (size_t)(s & 1) * BH) + aoff;
        ISS(0,h0p,0)    ISS(1,h0p,64)   ISS(2,h0p,128)  ISS(3,h0p,192)
        ISS(4,h0p,256)  ISS(5,h0p,320)  ISS(6,h0p,384)  ISS(7,h0p,448)
        ISS(8,h0p,512)  ISS(9,h0p,576)  ISS(10,h0p,640) ISS(11,h0p,704)
        ISS(12,h0p,768) ISS(13,h0p,832) ISS(14,h0p,896) ISS(15,h0p,960)
        VMW(15,0)  CON(0,0)   ISS(0,h0p,1024)
        VMW(15,1)  CON(1,1)   ISS(1,h0p,1088)
        VMW(15,2)  CON(2,2)   ISS(2,h0p,1152)
        VMW(15,3)  CON(3,3)   ISS(3,h0p,1216)
        VMW(15,4)  CON(4,4)   ISS(4,h0p,1280)
        VMW(15,5)  CON(5,5)   ISS(5,h0p,1344)
        VMW(15,6)  CON(6,6)   ISS(6,h0p,1408)
        VMW(15,7)  CON(7,7)   ISS(7,h0p,1472)
        VMW(15,8)  CON(8,8)   ISS(8,h0p,1536)
        VMW(15,9)  CON(9,9)   ISS(9,h0p,1600)
        VMW(15,10) CON(10,10) ISS(10,h0p,1664)
        VMW(15,11) CON(11,11) ISS(11,h0p,1728)
        VMW(15,12) CON(12,12) ISS(12,h0p,1792)
        VMW(15,13) CON(13,13) ISS(13,h0p,1856)
        VMW(15,14) CON(14,14) ISS(14,h0p,1920)
        VMW(15,15) CON(15,15) ISS(15,h0p,1984)
        VMW(15,0)  CON(0,16)  ISS(0,h1p,0)
        VMW(15,1)  CON(1,17)  ISS(1,h1p,64)
        VMW(15,2)  CON(2,18)  ISS(2,h1p,128)
        VMW(15,3)  CON(3,19)  ISS(3,h1p,192)
        VMW(15,4)  CON(4,20)  ISS(4,h1p,256)
        VMW(15,5)  CON(5,21)  ISS(5,h1p,320)
        VMW(15,6)  CON(6,22)  ISS(6,h1p,384)
        VMW(15,7)  CON(7,23)  ISS(7,h1p,448)
        VMW(15,8)  CON(8,24)  ISS(8,h1p,512)
        VMW(15,9)  CON(9,25)  ISS(9,h1p,576)
        VMW(15,10) CON(10,26) ISS(10,h1p,640)
        VMW(15,11) CON(11,27) ISS(11,h1p,704)
        VMW(15,12) CON(12,28) ISS(12,h1p,768)
        VMW(15,13) CON(13,29) ISS(13,h1p,832)
        VMW(15,14) CON(14,30) ISS(14,h1p,896)
        VMW(15,15) CON(15,31) ISS(15,h1p,960)
        VMW(15,0)  CON(0,32)  ISS(0,h1p,1024)
        VMW(15,1)  CON(1,33)  ISS(1,h1p,1088)
        VMW(15,2)  CON(2,34)  ISS(2,h1p,1152)
        VMW(15,3)  CON(3,35)  ISS(3,h1p,1216)
        VMW(15,4)  CON(4,36)  ISS(4,h1p,1280)
        VMW(15,5)  CON(5,37)  ISS(5,h1p,1344)
        VMW(15,6)  CON(6,38)  ISS(6,h1p,1408)
        VMW(15,7)  CON(7,39)  ISS(7,h1p,1472)
        VMW(15,8)  CON(8,40)  ISS(8,h1p,1536)
        VMW(15,9)  CON(9,41)  ISS(9,h1p,1600)
        VMW(15,10) CON(10,42) ISS(10,h1p,1664)
        VMW(15,11) CON(11,43) ISS(11,h1p,1728)
        VMW(15,12) CON(12,44) ISS(12,h1p,1792)
        VMW(15,13) CON(13,45) ISS(13,h1p,1856)
        VMW(15,14) CON(14,46) ISS(14,h1p,1920)
        VMW(15,15) CON(15,47) ISS(15,h1p,1984)
        VMW(15,0)  CON(0,48)
        VMW(14,1)  CON(1,49)
        VMW(13,2)  CON(2,50)
        VMW(12,3)  CON(3,51)
        VMW(11,4)  CON(4,52)
        VMW(10,5)  CON(5,53)
        VMW(9,6)   CON(6,54)
        VMW(8,7)   CON(7,55)
        VMW(7,8)   CON(8,56)
        VMW(6,9)   CON(9,57)
        VMW(5,10)  CON(10,58)
        VMW(4,11)  CON(11,59)
        VMW(3,12)  CON(12,60)
        VMW(2,13)  CON(13,61)
        VMW(1,14)  CON(14,62)
        VMW(0,15)  CON(15,63)
      }
#pragma unroll
      for (int r = 0; r < 4; ++r) {
        const int row = wave * 16 + (lane >> 4) * 4 + r;
        glds[row * 33 + r0]      = accA[r];
        glds[row * 33 + 16 + r0] = accB[r];
      }
      __syncthreads();

      const ushort* ig_ = p.ig + (size_t)(s & (TCHUNK - 1)) * (NBATCH * NGATE);
      float hres[2];
#pragma unroll
      for (int i = 0; i < 2; ++i) {
        const int jl = jl0 + i;
        float gi, gf, gg, go;
        if (!isL1) {
          gi = glds[eb * 33 + jl]      + bf2f(ig_[eb * 4096 + jj + i]);
          gf = glds[eb * 33 + 8 + jl]  + bf2f(ig_[eb * 4096 + 1024 + jj + i]);
          gg = glds[eb * 33 + 16 + jl] + bf2f(ig_[eb * 4096 + 2048 + jj + i]);
          go = glds[eb * 33 + 24 + jl] + bf2f(ig_[eb * 4096 + 3072 + jj + i]);
        } else {
          gi = glds[eb * 33 + jl]      + bias[0][i];
          gf = glds[eb * 33 + 8 + jl]  + bias[1][i];
          gg = glds[eb * 33 + 16 + jl] + bias[2][i];
          go = glds[eb * 33 + 24 + jl] + bias[3][i];
        }
        float c = creg[i];
        const float si = 1.f / (1.f + __expf(-gi));
        const float sf = 1.f / (1.f + __expf(-gf));
        const float so = 1.f / (1.f + __expf(-go));
        const float tg = tanhf(gg);
        c = sf * c + si * tg;
        hres[i] = so * tanhf(c);
        creg[i] = c;
      }

      const uint32_t packed = (uint32_t)f2bf(hres[0]) | ((uint32_t)f2bf(hres[1]) << 16);
      ushort* hdst = (!isL1) ? (p.h0r + (size_t)(s & 1) * BH)
                             : (p.h1r + (size_t)((s - 1) & 1) * BH);
      uint32_t* hw = (uint32_t*)(hdst + eb * 1024 + jj);
      __hip_atomic_store(hw, packed, __ATOMIC_RELAXED, __HIP_MEMORY_SCOPE_AGENT);
      // Same-address load-back: when this returns, the store is committed at the
      // coherence point (per-address FIFO). Kept live via empty asm.
      uint32_t chk = __hip_atomic_load(hw, __ATOMIC_RELAXED, __HIP_MEMORY_SCOPE_AGENT);
      asm volatile("" :: "v"(chk));

      if (isL1) {
#pragma unroll
        for (int i = 0; i < 2; ++i)
          p.out[(size_t)(s - 1) * BH + eb * 1024 + jj + i] = hres[i];
        if (s - 1 == T_STEPS - 1) {
#pragma unroll
          for (int i = 0; i < 2; ++i) {
            p.out[(size_t)TBH + BH + eb * 1024 + jj + i] = hres[i];
            p.out[(size_t)TBH + 3 * BH + eb * 1024 + jj + i] = creg[i];
          }
        }
      } else if (s == T_STEPS - 1) {
#pragma unroll
        for (int i = 0; i < 2; ++i) {
          p.out[(size_t)TBH + eb * 1024 + jj + i] = hres[i];
          p.out[(size_t)TBH + 2 * BH + eb * 1024 + jj + i] = creg[i];
        }
      }
    }
    gbar(p.bar, s - p.s0, stripe);
  }
#pragma unroll
  for (int i = 0; i < 2; ++i) cb_[eb * 1024 + jj + i] = creg[i];
}

// ---------------- host ----------------
extern "C" void kernel_launch(void* const* d_in, const int* in_sizes, int n_in,
                              void* d_out, int out_size, void* d_ws, size_t ws_size,
                              hipStream_t stream) {
  const float* x    = (const float*)d_in[0];
  const float* h0   = (const float*)d_in[1];
  const float* c0   = (const float*)d_in[2];
  const float* w_ih = (const float*)d_in[3];
  const float* w_hh = (const float*)d_in[4];
  const float* b_ih = (const float*)d_in[5];
  const float* b_hh = (const float*)d_in[6];
  float* out = (float*)d_out;

  ushort* xb    = (ushort*)d_ws;
  ushort* wihb  = xb + (size_t)TBH;
  ushort* whhb  = wihb + WEL;
  ushort* ig    = whhb + WEL;
  ushort* hinit = ig + (size_t)TCHUNK * NBATCH * NGATE;
  ushort* h0r   = hinit + 2 * (size_t)BH;
  ushort* h1r   = h0r + 2 * (size_t)BH;
  float*  cbuf  = (float*)(h1r + 2 * (size_t)BH);
  int*    bar   = (int*)(cbuf + 2 * (size_t)BH);

  const size_t need = ((size_t)TBH + 2 * WEL + (size_t)TCHUNK * NBATCH * NGATE
                       + 6 * (size_t)BH) * 2 + 2 * (size_t)BH * 4 + 1024;
  if (ws_size < need) return;  // loud failure: d_out stays poisoned

  { int n = TBH;          k_f32_to_bf16<<<(n / 4 + 255) / 256, 256, 0, stream>>>(x, xb, n); }
  { int n = (int)WEL;     k_f32_to_bf16<<<(n / 4 + 255) / 256, 256, 0, stream>>>(w_ih, wihb, n); }
  { int n = (int)WEL;     k_f32_to_bf16<<<(n / 4 + 255) / 256, 256, 0, stream>>>(w_hh, whhb, n); }
  { int n = 2 * BH;       k_f32_to_bf16<<<(n / 4 + 255) / 256, 256, 0, stream>>>(h0, hinit, n); }
  k_copy_f32<<<(2 * BH / 4 + 255) / 256, 256, 0, stream>>>(c0, cbuf, 2 * BH);

  ScanP sp;
  sp.wih1 = wihb + (size_t)NGATE * HID;
  sp.whh0 = whhb;
  sp.whh1 = whhb + (size_t)NGATE * HID;
  sp.ig = ig; sp.hinit = hinit;
  sp.h0r = h0r; sp.h1r = h1r; sp.cbuf = cbuf;
  sp.bi1 = b_ih + NGATE; sp.bh1 = b_hh + NGATE;
  sp.out = out; sp.bar = bar;

  const int bounds[5] = {0, 128, 256, 384, 513};
  for (int c = 0; c < 4; ++c) {
    k_zero<<<1, 256, 0, stream>>>(bar, 256);
    k_gemm_ig<<<dim3(64, 32), 256, 0, stream>>>(
        xb + (size_t)c * TCHUNK * NBATCH * HID, wihb, b_ih, b_hh, ig);
    sp.s0 = bounds[c]; sp.s1 = bounds[c + 1];
    void* kp[1] = {&sp};
    hipLaunchCooperativeKernel(reinterpret_cast<void*>(&k_scan),
                               dim3(NBLK), dim3(256), kp, 0, stream);
  }
}

// Round 8
// 6376.873 us; speedup vs baseline: 2.1067x; 1.3805x over previous
//
#include <hip/hip_runtime.h>
#include <hip/hip_bf16.h>
#include <stdint.h>

#define T_STEPS 512
#define NBATCH 64
#define HID 1024
#define NGATE 4096
#define NLAYERS 2
#define TCHUNK 128
#define BH (NBATCH * HID)            // 65536
#define TBH (T_STEPS * NBATCH * HID) // 33554432
#define WEL ((size_t)NLAYERS * NGATE * HID)
#define NBLK 256

typedef __attribute__((ext_vector_type(8))) short short8;
typedef __attribute__((ext_vector_type(4))) float f32x4;

__device__ __forceinline__ ushort f2bf(float f) {
  union { float f; uint32_t i; } u; u.f = f;
  return (ushort)((u.i + 0x7fffu + ((u.i >> 16) & 1u)) >> 16);  // RNE
}
__device__ __forceinline__ float bf2f(ushort b) {
  union { uint32_t i; float f; } u; u.i = ((uint32_t)b) << 16;
  return u.f;
}
__device__ __forceinline__ void gll16(const void* g, void* l) {
  __builtin_amdgcn_global_load_lds(
      (const __attribute__((address_space(1))) unsigned int*)g,
      (__attribute__((address_space(3))) unsigned int*)l, 16, 0, 0);
}

// ---- hand-rolled h-load pipeline (cross-XCD coherent sc0 sc1 loads) ----
// 16 rotating slots (64 VGPRs). Counted vmcnt per consume; the wait asm ties
// the slot register through it ("+v") so the MFMA data-depends on the WAIT.
#define ISS(SLOT, PTR, OFF) \
  asm volatile("global_load_dwordx4 %0, %1, off offset:" #OFF " sc0 sc1" \
               : "=v"(fr[SLOT]) : "v"(PTR));
#define VMW(N, SLOT) \
  asm volatile("s_waitcnt vmcnt(" #N ")" : "+v"(fr[SLOT]));
#define CON(SLOT, KC) { \
    const short8 b0v = *(const short8*)(bb0 + ((((KC) * 64) + kb) ^ bsw)); \
    const short8 b1v = *(const short8*)(bb1 + ((((KC) * 64) + kb) ^ bsw)); \
    accA = __builtin_amdgcn_mfma_f32_16x16x32_bf16(fr[SLOT], b0v, accA, 0, 0, 0); \
    accB = __builtin_amdgcn_mfma_f32_16x16x32_bf16(fr[SLOT], b1v, accB, 0, 0, 0); }

// ---------------- elementwise helpers ----------------
__global__ void k_f32_to_bf16(const float* __restrict__ in, ushort* __restrict__ out, int n) {
  int i = (blockIdx.x * blockDim.x + threadIdx.x) * 4;
  if (i >= n) return;
  const float4 v = *reinterpret_cast<const float4*>(in + i);
  ushort4 o; o.x = f2bf(v.x); o.y = f2bf(v.y); o.z = f2bf(v.z); o.w = f2bf(v.w);
  *reinterpret_cast<ushort4*>(out + i) = o;
}
__global__ void k_copy_f32(const float* __restrict__ in, float* __restrict__ out, int n) {
  int i = (blockIdx.x * blockDim.x + threadIdx.x) * 4;
  if (i >= n) return;
  *reinterpret_cast<float4*>(out + i) = *reinterpret_cast<const float4*>(in + i);
}
__global__ void k_zero(int* p, int n) {
  int i = blockIdx.x * blockDim.x + threadIdx.x;
  if (i < n) p[i] = 0;
}

// ---------------- igates GEMM (layer 0 only): C(8192,4096) = A @ W_ih0^T + b ----------------
__global__ __launch_bounds__(256) void k_gemm_ig(
    const ushort* __restrict__ A, const ushort* __restrict__ W,
    const float* __restrict__ bia, const float* __restrict__ bib,
    ushort* __restrict__ C)
{
  __shared__ __align__(16) ushort At[128 * 64];
  __shared__ __align__(16) ushort Bt[128 * 64];
  const int tid = threadIdx.x;
  const int wave = tid >> 6, lane = tid & 63;
  const int m0 = blockIdx.x * 128;
  const int n0 = blockIdx.y * 128;
  const int wr = wave >> 1, wc = wave & 1;

  const int r_st = wave * 8 + (lane >> 3);
  const int bsw = ((lane & 7) * 16) ^ ((r_st & 7) << 4);
  const ushort* aSrc = A + (size_t)(m0 + r_st) * 1024 + (bsw >> 1);
  const ushort* bSrc = W + (size_t)(n0 + r_st) * 1024 + (bsw >> 1);
  ushort* aDst = At + wave * 512;
  ushort* bDst = Bt + wave * 512;

  f32x4 acc[4][4];
#pragma unroll
  for (int a = 0; a < 4; ++a)
#pragma unroll
    for (int b = 0; b < 4; ++b) acc[a][b] = (f32x4){0.f, 0.f, 0.f, 0.f};

  for (int ks = 0; ks < 16; ++ks) {
#pragma unroll
    for (int i = 0; i < 4; ++i) {
      gll16(aSrc + (size_t)i * 32 * 1024 + ks * 64, aDst + i * 2048);
      gll16(bSrc + (size_t)i * 32 * 1024 + ks * 64, bDst + i * 2048);
    }
    __syncthreads();
#pragma unroll
    for (int kc = 0; kc < 2; ++kc) {
      const int kb = kc * 64 + (lane >> 4) * 16;
      short8 af[4], bfr[4];
#pragma unroll
      for (int mt = 0; mt < 4; ++mt) {
        const int r = wr * 64 + mt * 16 + (lane & 15);
        af[mt] = *(const short8*)((const char*)At + r * 128 + (kb ^ ((r & 7) << 4)));
      }
#pragma unroll
      for (int nt = 0; nt < 4; ++nt) {
        const int r = wc * 64 + nt * 16 + (lane & 15);
        bfr[nt] = *(const short8*)((const char*)Bt + r * 128 + (kb ^ ((r & 7) << 4)));
      }
#pragma unroll
      for (int mt = 0; mt < 4; ++mt)
#pragma unroll
        for (int nt = 0; nt < 4; ++nt)
          acc[mt][nt] = __builtin_amdgcn_mfma_f32_16x16x32_bf16(af[mt], bfr[nt], acc[mt][nt], 0, 0, 0);
    }
    __syncthreads();
  }

#pragma unroll
  for (int nt = 0; nt < 4; ++nt) {
    const int col = n0 + wc * 64 + nt * 16 + (lane & 15);
    const float bias = bia[col] + bib[col];
#pragma unroll
    for (int mt = 0; mt < 4; ++mt) {
      const int row = m0 + wr * 64 + mt * 16 + (lane >> 4) * 4;
      const f32x4 v = acc[mt][nt];
#pragma unroll
      for (int r = 0; r < 4; ++r)
        C[(size_t)(row + r) * 4096 + col] = f2bf(v[r] + bias);
    }
  }
}

// ---------------- persistent pipelined scan ----------------
struct ScanP {
  const ushort* wih1; const ushort* whh0; const ushort* whh1;
  const ushort* ig;   const ushort* hinit;
  ushort* h0r; ushort* h1r; float* cbuf;
  const float* bi1; const float* bh1;
  float* out; int* bar; int s0; int s1;
};

// Root+release barrier. Arrivals: 16 monotonic stripe counters (no resets,
// relaxed-only -- same induction-sound scheme as before). ONLY block 0 polls
// the stripes (16 pipelined loads = 1 RT/round); it then publishes a single
// monotonic release word. All other blocks poll that ONE word with long sleeps.
// This removes the 256-poller x 4-hot-line HBM-latency polling storm that
// dominated round 7 (~3 MB/step of poll FETCH traffic).
__device__ __forceinline__ void gbar(int* bar, int phase, int stripe, bool isRoot) {
  __syncthreads();
  if (threadIdx.x == 0) {
    __hip_atomic_fetch_add(bar + stripe * 16, 1, __ATOMIC_RELAXED, __HIP_MEMORY_SCOPE_AGENT);
    if (isRoot) {
      const int target = (phase + 1) * NBLK;
      for (;;) {
        int sum = 0;
#pragma unroll
        for (int i = 0; i < 16; ++i)
          sum += __hip_atomic_load(bar + i * 16, __ATOMIC_RELAXED, __HIP_MEMORY_SCOPE_AGENT);
        if (sum >= target) break;
        __builtin_amdgcn_s_sleep(1);
      }
      __hip_atomic_store(bar + 256, phase + 1, __ATOMIC_RELAXED, __HIP_MEMORY_SCOPE_AGENT);
    } else {
      while (__hip_atomic_load(bar + 256, __ATOMIC_RELAXED, __HIP_MEMORY_SCOPE_AGENT) < phase + 1)
        __builtin_amdgcn_s_sleep(8);
    }
  }
  __syncthreads();
  __builtin_amdgcn_sched_barrier(0);
}

// 256 blocks x 256 threads. Blocks 0..127: layer0 step s. Blocks 128..255: layer1 step s-1
// (K=2048 fused [W_ih1|W_hh1], A = [h0_{s-1} ; h1_{s-2}]). W staged once in LDS.
__global__ __launch_bounds__(256, 1) void k_scan(ScanP p) {
  __shared__ __align__(16) ushort Wl[32 * 2048];  // 128 KB
  __shared__ float glds[64 * 33];
  const int tid = threadIdx.x, wave = tid >> 6, lane = tid & 63;
  const bool isL1 = blockIdx.x >= 128;
  const int cb = isL1 ? (int)blockIdx.x - 128 : (int)blockIdx.x;
  const int j0 = cb * 8;
  const int stripe = blockIdx.x & 15;
  const bool isRoot = (blockIdx.x == 0);

  if (isL1) {
    for (int q = wave; q < 128; q += 4) {
      const int i = q >> 2, ch = q & 3;
      const ushort* base = (ch < 2) ? p.wih1 : p.whh1;
      const int g = (i >> 3) * 1024 + j0 + (i & 7);
      gll16(base + (size_t)g * 1024 + (ch & 1) * 512 + (((lane * 16) ^ ((i & 7) << 4)) >> 1),
            (char*)Wl + i * 4096 + ch * 1024);
    }
  } else {
    for (int q = wave; q < 64; q += 4) {
      const int i = q >> 1, ch = q & 1;
      const int g = (i >> 3) * 1024 + j0 + (i & 7);
      gll16(p.whh0 + (size_t)g * 1024 + ch * 512 + (((lane * 16) ^ ((i & 7) << 4)) >> 1),
            (char*)Wl + i * 4096 + ch * 1024);
    }
  }

  // Epilogue geometry: thread owns (b = tid>>2, j = j0 + (tid&3)*2 + {0,1})
  const int eb  = tid >> 2;
  const int jl0 = (tid & 3) * 2;
  const int jj  = j0 + jl0;
  float* cb_ = p.cbuf + (isL1 ? BH : 0);
  float creg[2], bias[4][2];
#pragma unroll
  for (int i = 0; i < 2; ++i) creg[i] = cb_[eb * 1024 + jj + i];
  if (isL1) {
#pragma unroll
    for (int g = 0; g < 4; ++g)
#pragma unroll
      for (int i = 0; i < 2; ++i)
        bias[g][i] = p.bi1[g * 1024 + jj + i] + p.bh1[g * 1024 + jj + i];
  }

  const size_t aoff = (size_t)(wave * 16 + (lane & 15)) * 1024 + (size_t)((lane >> 4) * 8);
  const int r0 = lane & 15;
  const char* bb0 = (const char*)Wl + r0 * 4096;
  const char* bb1 = (const char*)Wl + (r0 + 16) * 4096;
  const int bsw = (r0 & 7) << 4;
  const int kb = (lane >> 4) * 16;

  __syncthreads();  // W staged (vmcnt drained)

  for (int s = p.s0; s < p.s1; ++s) {
    const bool act = isL1 ? (s >= 1) : (s < T_STEPS);
    if (act) {
      f32x4 accA = {0.f, 0.f, 0.f, 0.f}, accB = {0.f, 0.f, 0.f, 0.f};
      short8 fr[16];
      if (!isL1) {
        const ushort* hp = (((s == 0) ? p.hinit : p.h0r + (size_t)((s - 1) & 1) * BH)) + aoff;
        ISS(0,hp,0)    ISS(1,hp,64)   ISS(2,hp,128)  ISS(3,hp,192)
        ISS(4,hp,256)  ISS(5,hp,320)  ISS(6,hp,384)  ISS(7,hp,448)
        ISS(8,hp,512)  ISS(9,hp,576)  ISS(10,hp,640) ISS(11,hp,704)
        ISS(12,hp,768) ISS(13,hp,832) ISS(14,hp,896) ISS(15,hp,960)
        VMW(15,0)  CON(0,0)   ISS(0,hp,1024)
        VMW(15,1)  CON(1,1)   ISS(1,hp,1088)
        VMW(15,2)  CON(2,2)   ISS(2,hp,1152)
        VMW(15,3)  CON(3,3)   ISS(3,hp,1216)
        VMW(15,4)  CON(4,4)   ISS(4,hp,1280)
        VMW(15,5)  CON(5,5)   ISS(5,hp,1344)
        VMW(15,6)  CON(6,6)   ISS(6,hp,1408)
        VMW(15,7)  CON(7,7)   ISS(7,hp,1472)
        VMW(15,8)  CON(8,8)   ISS(8,hp,1536)
        VMW(15,9)  CON(9,9)   ISS(9,hp,1600)
        VMW(15,10) CON(10,10) ISS(10,hp,1664)
        VMW(15,11) CON(11,11) ISS(11,hp,1728)
        VMW(15,12) CON(12,12) ISS(12,hp,1792)
        VMW(15,13) CON(13,13) ISS(13,hp,1856)
        VMW(15,14) CON(14,14) ISS(14,hp,1920)
        VMW(15,15) CON(15,15) ISS(15,hp,1984)
        VMW(15,0)  CON(0,16)
        VMW(14,1)  CON(1,17)
        VMW(13,2)  CON(2,18)
        VMW(12,3)  CON(3,19)
        VMW(11,4)  CON(4,20)
        VMW(10,5)  CON(5,21)
        VMW(9,6)   CON(6,22)
        VMW(8,7)   CON(7,23)
        VMW(7,8)   CON(8,24)
        VMW(6,9)   CON(9,25)
        VMW(5,10)  CON(10,26)
        VMW(4,11)  CON(11,27)
        VMW(3,12)  CON(12,28)
        VMW(2,13)  CON(13,29)
        VMW(1,14)  CON(14,30)
        VMW(0,15)  CON(15,31)
      } else {
        const ushort* h0p = p.h0r + (size_t)((s - 1) & 1) * BH + aoff;
        const ushort* h1p = ((s == 1) ? p.hinit + BH : p.h1r + (size_t)(s & 1) * BH) + aoff;
        ISS(0,h0p,0)    ISS(1,h0p,64)   ISS(2,h0p,128)  ISS(3,h0p,192)
        ISS(4,h0p,256)  ISS(5,h0p,320)  ISS(6,h0p,384)  ISS(7,h0p,448)
        ISS(8,h0p,512)  ISS(9,h0p,576)  ISS(10,h0p,640) ISS(11,h0p,704)
        ISS(12,h0p,768) ISS(13,h0p,832) ISS(14,h0p,896) ISS(15,h0p,960)
        VMW(15,0)  CON(0,0)   ISS(0,h0p,1024)
        VMW(15,1)  CON(1,1)   ISS(1,h0p,1088)
        VMW(15,2)  CON(2,2)   ISS(2,h0p,1152)
        VMW(15,3)  CON(3,3)   ISS(3,h0p,1216)
        VMW(15,4)  CON(4,4)   ISS(4,h0p,1280)
        VMW(15,5)  CON(5,5)   ISS(5,h0p,1344)
        VMW(15,6)  CON(6,6)   ISS(6,h0p,1408)
        VMW(15,7)  CON(7,7)   ISS(7,h0p,1472)
        VMW(15,8)  CON(8,8)   ISS(8,h0p,1536)
        VMW(15,9)  CON(9,9)   ISS(9,h0p,1600)
        VMW(15,10) CON(10,10) ISS(10,h0p,1664)
        VMW(15,11) CON(11,11) ISS(11,h0p,1728)
        VMW(15,12) CON(12,12) ISS(12,h0p,1792)
        VMW(15,13) CON(13,13) ISS(13,h0p,1856)
        VMW(15,14) CON(14,14) ISS(14,h0p,1920)
        VMW(15,15) CON(15,15) ISS(15,h0p,1984)
        VMW(15,0)  CON(0,16)  ISS(0,h1p,0)
        VMW(15,1)  CON(1,17)  ISS(1,h1p,64)
        VMW(15,2)  CON(2,18)  ISS(2,h1p,128)
        VMW(15,3)  CON(3,19)  ISS(3,h1p,192)
        VMW(15,4)  CON(4,20)  ISS(4,h1p,256)
        VMW(15,5)  CON(5,21)  ISS(5,h1p,320)
        VMW(15,6)  CON(6,22)  ISS(6,h1p,384)
        VMW(15,7)  CON(7,23)  ISS(7,h1p,448)
        VMW(15,8)  CON(8,24)  ISS(8,h1p,512)
        VMW(15,9)  CON(9,25)  ISS(9,h1p,576)
        VMW(15,10) CON(10,26) ISS(10,h1p,640)
        VMW(15,11) CON(11,27) ISS(11,h1p,704)
        VMW(15,12) CON(12,28) ISS(12,h1p,768)
        VMW(15,13) CON(13,29) ISS(13,h1p,832)
        VMW(15,14) CON(14,30) ISS(14,h1p,896)
        VMW(15,15) CON(15,31) ISS(15,h1p,960)
        VMW(15,0)  CON(0,32)  ISS(0,h1p,1024)
        VMW(15,1)  CON(1,33)  ISS(1,h1p,1088)
        VMW(15,2)  CON(2,34)  ISS(2,h1p,1152)
        VMW(15,3)  CON(3,35)  ISS(3,h1p,1216)
        VMW(15,4)  CON(4,36)  ISS(4,h1p,1280)
        VMW(15,5)  CON(5,37)  ISS(5,h1p,1344)
        VMW(15,6)  CON(6,38)  ISS(6,h1p,1408)
        VMW(15,7)  CON(7,39)  ISS(7,h1p,1472)
        VMW(15,8)  CON(8,40)  ISS(8,h1p,1536)
        VMW(15,9)  CON(9,41)  ISS(9,h1p,1600)
        VMW(15,10) CON(10,42) ISS(10,h1p,1664)
        VMW(15,11) CON(11,43) ISS(11,h1p,1728)
        VMW(15,12) CON(12,44) ISS(12,h1p,1792)
        VMW(15,13) CON(13,45) ISS(13,h1p,1856)
        VMW(15,14) CON(14,46) ISS(14,h1p,1920)
        VMW(15,15) CON(15,47) ISS(15,h1p,1984)
        VMW(15,0)  CON(0,48)
        VMW(14,1)  CON(1,49)
        VMW(13,2)  CON(2,50)
        VMW(12,3)  CON(3,51)
        VMW(11,4)  CON(4,52)
        VMW(10,5)  CON(5,53)
        VMW(9,6)   CON(6,54)
        VMW(8,7)   CON(7,55)
        VMW(7,8)   CON(8,56)
        VMW(6,9)   CON(9,57)
        VMW(5,10)  CON(10,58)
        VMW(4,11)  CON(11,59)
        VMW(3,12)  CON(12,60)
        VMW(2,13)  CON(13,61)
        VMW(1,14)  CON(14,62)
        VMW(0,15)  CON(15,63)
      }
#pragma unroll
      for (int r = 0; r < 4; ++r) {
        const int row = wave * 16 + (lane >> 4) * 4 + r;
        glds[row * 33 + r0]      = accA[r];
        glds[row * 33 + 16 + r0] = accB[r];
      }
      __syncthreads();

      const ushort* ig_ = p.ig + (size_t)(s & (TCHUNK - 1)) * (NBATCH * NGATE);
      float hres[2];
#pragma unroll
      for (int i = 0; i < 2; ++i) {
        const int jl = jl0 + i;
        float gi, gf, gg, go;
        if (!isL1) {
          gi = glds[eb * 33 + jl]      + bf2f(ig_[eb * 4096 + jj + i]);
          gf = glds[eb * 33 + 8 + jl]  + bf2f(ig_[eb * 4096 + 1024 + jj + i]);
          gg = glds[eb * 33 + 16 + jl] + bf2f(ig_[eb * 4096 + 2048 + jj + i]);
          go = glds[eb * 33 + 24 + jl] + bf2f(ig_[eb * 4096 + 3072 + jj + i]);
        } else {
          gi = glds[eb * 33 + jl]      + bias[0][i];
          gf = glds[eb * 33 + 8 + jl]  + bias[1][i];
          gg = glds[eb * 33 + 16 + jl] + bias[2][i];
          go = glds[eb * 33 + 24 + jl] + bias[3][i];
        }
        float c = creg[i];
        const float si = 1.f / (1.f + __expf(-gi));
        const float sf = 1.f / (1.f + __expf(-gf));
        const float so = 1.f / (1.f + __expf(-go));
        const float tg = tanhf(gg);
        c = sf * c + si * tg;
        hres[i] = so * tanhf(c);
        creg[i] = c;
      }

      const uint32_t packed = (uint32_t)f2bf(hres[0]) | ((uint32_t)f2bf(hres[1]) << 16);
      ushort* hdst = (!isL1) ? (p.h0r + (size_t)(s & 1) * BH)
                             : (p.h1r + (size_t)((s - 1) & 1) * BH);
      uint32_t* hw = (uint32_t*)(hdst + eb * 1024 + jj);
      __hip_atomic_store(hw, packed, __ATOMIC_RELAXED, __HIP_MEMORY_SCOPE_AGENT);
      // Same-address load-back: when this returns, the store is committed at the
      // coherence point (per-address FIFO). Kept live via empty asm.
      uint32_t chk = __hip_atomic_load(hw, __ATOMIC_RELAXED, __HIP_MEMORY_SCOPE_AGENT);
      asm volatile("" :: "v"(chk));

      if (isL1) {
#pragma unroll
        for (int i = 0; i < 2; ++i)
          p.out[(size_t)(s - 1) * BH + eb * 1024 + jj + i] = hres[i];
        if (s - 1 == T_STEPS - 1) {
#pragma unroll
          for (int i = 0; i < 2; ++i) {
            p.out[(size_t)TBH + BH + eb * 1024 + jj + i] = hres[i];
            p.out[(size_t)TBH + 3 * BH + eb * 1024 + jj + i] = creg[i];
          }
        }
      } else if (s == T_STEPS - 1) {
#pragma unroll
        for (int i = 0; i < 2; ++i) {
          p.out[(size_t)TBH + eb * 1024 + jj + i] = hres[i];
          p.out[(size_t)TBH + 2 * BH + eb * 1024 + jj + i] = creg[i];
        }
      }
    }
    gbar(p.bar, s - p.s0, stripe, isRoot);
  }
#pragma unroll
  for (int i = 0; i < 2; ++i) cb_[eb * 1024 + jj + i] = creg[i];
}

// ---------------- host ----------------
extern "C" void kernel_launch(void* const* d_in, const int* in_sizes, int n_in,
                              void* d_out, int out_size, void* d_ws, size_t ws_size,
                              hipStream_t stream) {
  const float* x    = (const float*)d_in[0];
  const float* h0   = (const float*)d_in[1];
  const float* c0   = (const float*)d_in[2];
  const float* w_ih = (const float*)d_in[3];
  const float* w_hh = (const float*)d_in[4];
  const float* b_ih = (const float*)d_in[5];
  const float* b_hh = (const float*)d_in[6];
  float* out = (float*)d_out;

  ushort* xb    = (ushort*)d_ws;
  ushort* wihb  = xb + (size_t)TBH;
  ushort* whhb  = wihb + WEL;
  ushort* ig    = whhb + WEL;
  ushort* hinit = ig + (size_t)TCHUNK * NBATCH * NGATE;
  ushort* h0r   = hinit + 2 * (size_t)BH;
  ushort* h1r   = h0r + 2 * (size_t)BH;
  float*  cbuf  = (float*)(h1r + 2 * (size_t)BH);
  int*    bar   = (int*)(cbuf + 2 * (size_t)BH);

  const size_t need = ((size_t)TBH + 2 * WEL + (size_t)TCHUNK * NBATCH * NGATE
                       + 6 * (size_t)BH) * 2 + 2 * (size_t)BH * 4 + 4096;
  if (ws_size < need) return;  // loud failure: d_out stays poisoned

  { int n = TBH;          k_f32_to_bf16<<<(n / 4 + 255) / 256, 256, 0, stream>>>(x, xb, n); }
  { int n = (int)WEL;     k_f32_to_bf16<<<(n / 4 + 255) / 256, 256, 0, stream>>>(w_ih, wihb, n); }
  { int n = (int)WEL;     k_f32_to_bf16<<<(n / 4 + 255) / 256, 256, 0, stream>>>(w_hh, whhb, n); }
  { int n = 2 * BH;       k_f32_to_bf16<<<(n / 4 + 255) / 256, 256, 0, stream>>>(h0, hinit, n); }
  k_copy_f32<<<(2 * BH / 4 + 255) / 256, 256, 0, stream>>>(c0, cbuf, 2 * BH);

  ScanP sp;
  sp.wih1 = wihb + (size_t)NGATE * HID;
  sp.whh0 = whhb;
  sp.whh1 = whhb + (size_t)NGATE * HID;
  sp.ig = ig; sp.hinit = hinit;
  sp.h0r = h0r; sp.h1r = h1r; sp.cbuf = cbuf;
  sp.bi1 = b_ih + NGATE; sp.bh1 = b_hh + NGATE;
  sp.out = out; sp.bar = bar;

  const int bounds[5] = {0, 128, 256, 384, 513};
  for (int c = 0; c < 4; ++c) {
    k_zero<<<2, 256, 0, stream>>>(bar, 512);
    k_gemm_ig<<<dim3(64, 32), 256, 0, stream>>>(
        xb + (size_t)c * TCHUNK * NBATCH * HID, wihb, b_ih, b_hh, ig);
    sp.s0 = bounds[c]; sp.s1 = bounds[c + 1];
    void* kp[1] = {&sp};
    hipLaunchCooperativeKernel(reinterpret_cast<void*>(&k_scan),
                               dim3(NBLK), dim3(256), kp, 0, stream);
  }
}

// Round 9
// 5995.036 us; speedup vs baseline: 2.2408x; 1.0637x over previous
//
#include <hip/hip_runtime.h>
#include <hip/hip_bf16.h>
#include <stdint.h>

#define T_STEPS 512
#define NBATCH 64
#define HID 1024
#define NGATE 4096
#define NLAYERS 2
#define BH (NBATCH * HID)            // 65536
#define TBH (T_STEPS * NBATCH * HID) // 33554432
#define WEL ((size_t)NLAYERS * NGATE * HID)
#define NBLK 256

typedef __attribute__((ext_vector_type(8))) short short8;
typedef __attribute__((ext_vector_type(4))) float f32x4;

__device__ __forceinline__ ushort f2bf(float f) {
  union { float f; uint32_t i; } u; u.f = f;
  return (ushort)((u.i + 0x7fffu + ((u.i >> 16) & 1u)) >> 16);  // RNE
}
__device__ __forceinline__ float bf2f(ushort b) {
  union { uint32_t i; float f; } u; u.i = ((uint32_t)b) << 16;
  return u.f;
}
__device__ __forceinline__ void gll16(const void* g, void* l) {
  __builtin_amdgcn_global_load_lds(
      (const __attribute__((address_space(1))) unsigned int*)g,
      (__attribute__((address_space(3))) unsigned int*)l, 16, 0, 0);
}

// ---- hand-rolled A-load pipeline: 16 rotating slots, counted vmcnt ----
// ISSC = normal cached load (L2-shared per XCD; safe for never-rewritten
// addresses: x, h0 ring). ISSU = sc0 sc1 cross-XCD-coherent load (h1 double
// buffer, addresses reused every 2 phases). The VMW wait ties the slot
// register through the asm ("+v") so the MFMA data-depends on the WAIT.
// vmcnt retires in issue order; foreign VMEM only strengthens the waits.
#define ISSC(SLOT, PTR, OFF) \
  asm volatile("global_load_dwordx4 %0, %1, off offset:" #OFF \
               : "=v"(fr[SLOT]) : "v"(PTR));
#define ISSU(SLOT, PTR, OFF) \
  asm volatile("global_load_dwordx4 %0, %1, off offset:" #OFF " sc0 sc1" \
               : "=v"(fr[SLOT]) : "v"(PTR));
#define VMW(N, SLOT) \
  asm volatile("s_waitcnt vmcnt(" #N ")" : "+v"(fr[SLOT]));
#define CON(SLOT, KC) { \
    const short8 b0v = *(const short8*)(bb0 + ((((KC) * 64) + kb) ^ bsw)); \
    const short8 b1v = *(const short8*)(bb1 + ((((KC) * 64) + kb) ^ bsw)); \
    accA = __builtin_amdgcn_mfma_f32_16x16x32_bf16(fr[SLOT], b0v, accA, 0, 0, 0); \
    accB = __builtin_amdgcn_mfma_f32_16x16x32_bf16(fr[SLOT], b1v, accB, 0, 0, 0); }

// 64-fragment K=2048 schedule (proven round-7/8 structure). A0p covers
// K 0..1023 (kc 0..31), A1p covers K 1024..2047 (kc 32..63). M0/M1 select
// the load flavor per pointer.
#define PIPE64(M0, M1) \
  M0(0,A0p,0)    M0(1,A0p,64)   M0(2,A0p,128)  M0(3,A0p,192)  \
  M0(4,A0p,256)  M0(5,A0p,320)  M0(6,A0p,384)  M0(7,A0p,448)  \
  M0(8,A0p,512)  M0(9,A0p,576)  M0(10,A0p,640) M0(11,A0p,704) \
  M0(12,A0p,768) M0(13,A0p,832) M0(14,A0p,896) M0(15,A0p,960) \
  VMW(15,0)  CON(0,0)   M0(0,A0p,1024)  \
  VMW(15,1)  CON(1,1)   M0(1,A0p,1088)  \
  VMW(15,2)  CON(2,2)   M0(2,A0p,1152)  \
  VMW(15,3)  CON(3,3)   M0(3,A0p,1216)  \
  VMW(15,4)  CON(4,4)   M0(4,A0p,1280)  \
  VMW(15,5)  CON(5,5)   M0(5,A0p,1344)  \
  VMW(15,6)  CON(6,6)   M0(6,A0p,1408)  \
  VMW(15,7)  CON(7,7)   M0(7,A0p,1472)  \
  VMW(15,8)  CON(8,8)   M0(8,A0p,1536)  \
  VMW(15,9)  CON(9,9)   M0(9,A0p,1600)  \
  VMW(15,10) CON(10,10) M0(10,A0p,1664) \
  VMW(15,11) CON(11,11) M0(11,A0p,1728) \
  VMW(15,12) CON(12,12) M0(12,A0p,1792) \
  VMW(15,13) CON(13,13) M0(13,A0p,1856) \
  VMW(15,14) CON(14,14) M0(14,A0p,1920) \
  VMW(15,15) CON(15,15) M0(15,A0p,1984) \
  VMW(15,0)  CON(0,16)  M1(0,A1p,0)     \
  VMW(15,1)  CON(1,17)  M1(1,A1p,64)    \
  VMW(15,2)  CON(2,18)  M1(2,A1p,128)   \
  VMW(15,3)  CON(3,19)  M1(3,A1p,192)   \
  VMW(15,4)  CON(4,20)  M1(4,A1p,256)   \
  VMW(15,5)  CON(5,21)  M1(5,A1p,320)   \
  VMW(15,6)  CON(6,22)  M1(6,A1p,384)   \
  VMW(15,7)  CON(7,23)  M1(7,A1p,448)   \
  VMW(15,8)  CON(8,24)  M1(8,A1p,512)   \
  VMW(15,9)  CON(9,25)  M1(9,A1p,576)   \
  VMW(15,10) CON(10,26) M1(10,A1p,640)  \
  VMW(15,11) CON(11,27) M1(11,A1p,704)  \
  VMW(15,12) CON(12,28) M1(12,A1p,768)  \
  VMW(15,13) CON(13,29) M1(13,A1p,832)  \
  VMW(15,14) CON(14,30) M1(14,A1p,896)  \
  VMW(15,15) CON(15,31) M1(15,A1p,960)  \
  VMW(15,0)  CON(0,32)  M1(0,A1p,1024)  \
  VMW(15,1)  CON(1,33)  M1(1,A1p,1088)  \
  VMW(15,2)  CON(2,34)  M1(2,A1p,1152)  \
  VMW(15,3)  CON(3,35)  M1(3,A1p,1216)  \
  VMW(15,4)  CON(4,36)  M1(4,A1p,1280)  \
  VMW(15,5)  CON(5,37)  M1(5,A1p,1344)  \
  VMW(15,6)  CON(6,38)  M1(6,A1p,1408)  \
  VMW(15,7)  CON(7,39)  M1(7,A1p,1472)  \
  VMW(15,8)  CON(8,40)  M1(8,A1p,1536)  \
  VMW(15,9)  CON(9,41)  M1(9,A1p,1600)  \
  VMW(15,10) CON(10,42) M1(10,A1p,1664) \
  VMW(15,11) CON(11,43) M1(11,A1p,1728) \
  VMW(15,12) CON(12,44) M1(12,A1p,1792) \
  VMW(15,13) CON(13,45) M1(13,A1p,1856) \
  VMW(15,14) CON(14,46) M1(14,A1p,1920) \
  VMW(15,15) CON(15,47) M1(15,A1p,1984) \
  VMW(15,0)  CON(0,48)  \
  VMW(14,1)  CON(1,49)  \
  VMW(13,2)  CON(2,50)  \
  VMW(12,3)  CON(3,51)  \
  VMW(11,4)  CON(4,52)  \
  VMW(10,5)  CON(5,53)  \
  VMW(9,6)   CON(6,54)  \
  VMW(8,7)   CON(7,55)  \
  VMW(7,8)   CON(8,56)  \
  VMW(6,9)   CON(9,57)  \
  VMW(5,10)  CON(10,58) \
  VMW(4,11)  CON(11,59) \
  VMW(3,12)  CON(12,60) \
  VMW(2,13)  CON(13,61) \
  VMW(1,14)  CON(14,62) \
  VMW(0,15)  CON(15,63)

// ---------------- elementwise helpers ----------------
__global__ void k_f32_to_bf16(const float* __restrict__ in, ushort* __restrict__ out, int n) {
  int i = (blockIdx.x * blockDim.x + threadIdx.x) * 4;
  if (i >= n) return;
  const float4 v = *reinterpret_cast<const float4*>(in + i);
  ushort4 o; o.x = f2bf(v.x); o.y = f2bf(v.y); o.z = f2bf(v.z); o.w = f2bf(v.w);
  *reinterpret_cast<ushort4*>(out + i) = o;
}
__global__ void k_zero(int* p, int n) {
  int i = blockIdx.x * blockDim.x + threadIdx.x;
  if (i < n) p[i] = 0;
}

// ---------------- persistent fused scan (both layers, both GEMMs) ----------------
struct ScanP {
  const ushort* wih; const ushort* whh;   // bf16 weights, layer-strided
  const ushort* xb;  const ushort* hinit; // x sequence; [h0_init ; h1_init]
  ushort* h0r;                            // layer-0 h ring, one slot per step
  ushort* h1d;                            // layer-1 h double buffer
  const float* c0; const float* bi; const float* bh;
  float* out; int* bar;
};

// Root+release barrier (monotonic, relaxed-only, no resets).
__device__ __forceinline__ void gbar(int* bar, int phase, int stripe, bool isRoot) {
  __syncthreads();
  if (threadIdx.x == 0) {
    __hip_atomic_fetch_add(bar + stripe * 16, 1, __ATOMIC_RELAXED, __HIP_MEMORY_SCOPE_AGENT);
    if (isRoot) {
      const int target = (phase + 1) * NBLK;
      for (;;) {
        int sum = 0;
#pragma unroll
        for (int i = 0; i < 16; ++i)
          sum += __hip_atomic_load(bar + i * 16, __ATOMIC_RELAXED, __HIP_MEMORY_SCOPE_AGENT);
        if (sum >= target) break;
        __builtin_amdgcn_s_sleep(1);
      }
      __hip_atomic_store(bar + 256, phase + 1, __ATOMIC_RELAXED, __HIP_MEMORY_SCOPE_AGENT);
    } else {
      while (__hip_atomic_load(bar + 256, __ATOMIC_RELAXED, __HIP_MEMORY_SCOPE_AGENT) < phase + 1)
        __builtin_amdgcn_s_sleep(4);
    }
  }
  __syncthreads();
  __builtin_amdgcn_sched_barrier(0);
}

// 256 blocks x 256 threads, single launch, 513 phases.
// Blocks 0..127 = layer 0 at step s:  gates = [x_s ; h0_{s-1}] @ [W_ih0 | W_hh0]^T
// Blocks 128..255 = layer 1 at step s-1: gates = [h0_{s-1} ; h1_{s-2}] @ [W_ih1 | W_hh1]^T
// Each block owns 8 h-cols x 4 gates = 32 gate rows; W slice (128 KB) in LDS.
__global__ __launch_bounds__(256, 1) void k_scan(ScanP p) {
  __shared__ __align__(16) ushort Wl[32 * 2048];  // 128 KB
  __shared__ float glds[64 * 33];
  const int tid = threadIdx.x, wave = tid >> 6, lane = tid & 63;
  const bool isL1 = blockIdx.x >= 128;
  const int cb = isL1 ? (int)blockIdx.x - 128 : (int)blockIdx.x;
  const int j0 = cb * 8;
  const int stripe = blockIdx.x & 15;
  const bool isRoot = (blockIdx.x == 0);

  const ushort* wihL = p.wih + (isL1 ? (size_t)NGATE * HID : 0);
  const ushort* whhL = p.whh + (isL1 ? (size_t)NGATE * HID : 0);
  for (int q = wave; q < 128; q += 4) {
    const int i = q >> 2, ch = q & 3;
    const ushort* base = (ch < 2) ? wihL : whhL;
    const int g = (i >> 3) * 1024 + j0 + (i & 7);
    gll16(base + (size_t)g * 1024 + (ch & 1) * 512 + (((lane * 16) ^ ((i & 7) << 4)) >> 1),
          (char*)Wl + i * 4096 + ch * 1024);
  }

  // Epilogue geometry: thread owns (b = tid>>2, j = j0 + (tid&3)*2 + {0,1})
  const int eb  = tid >> 2;
  const int jl0 = (tid & 3) * 2;
  const int jj  = j0 + jl0;
  const int lofs = isL1 ? NGATE : 0;
  float creg[2], bias[4][2];
#pragma unroll
  for (int i = 0; i < 2; ++i) creg[i] = p.c0[(isL1 ? BH : 0) + eb * 1024 + jj + i];
#pragma unroll
  for (int g = 0; g < 4; ++g)
#pragma unroll
    for (int i = 0; i < 2; ++i)
      bias[g][i] = p.bi[lofs + g * 1024 + jj + i] + p.bh[lofs + g * 1024 + jj + i];

  const size_t aoff = (size_t)(wave * 16 + (lane & 15)) * 1024 + (size_t)((lane >> 4) * 8);
  const int r0 = lane & 15;
  const char* bb0 = (const char*)Wl + r0 * 4096;
  const char* bb1 = (const char*)Wl + (r0 + 16) * 4096;
  const int bsw = (r0 & 7) << 4;
  const int kb = (lane >> 4) * 16;

  __syncthreads();  // W staged (vmcnt drained)

  for (int s = 0; s < T_STEPS + 1; ++s) {
    const bool act = isL1 ? (s >= 1) : (s < T_STEPS);
    if (act) {
      f32x4 accA = {0.f, 0.f, 0.f, 0.f}, accB = {0.f, 0.f, 0.f, 0.f};
      short8 fr[16];
      if (!isL1) {
        const ushort* A0p = p.xb + (size_t)s * BH + aoff;                       // x_s (static)
        const ushort* A1p = ((s == 0) ? p.hinit : p.h0r + (size_t)(s - 1) * BH) + aoff;  // ring
        PIPE64(ISSC, ISSC)
      } else {
        const ushort* A0p = p.h0r + (size_t)(s - 1) * BH + aoff;                // ring (fresh)
        const ushort* A1p = ((s == 1) ? p.hinit + BH : p.h1d + (size_t)(s & 1) * BH) + aoff;
        PIPE64(ISSC, ISSU)
      }
#pragma unroll
      for (int r = 0; r < 4; ++r) {
        const int row = wave * 16 + (lane >> 4) * 4 + r;
        glds[row * 33 + r0]      = accA[r];
        glds[row * 33 + 16 + r0] = accB[r];
      }
      __syncthreads();

      float hres[2];
#pragma unroll
      for (int i = 0; i < 2; ++i) {
        const int jl = jl0 + i;
        const float gi = glds[eb * 33 + jl]      + bias[0][i];
        const float gf = glds[eb * 33 + 8 + jl]  + bias[1][i];
        const float gg = glds[eb * 33 + 16 + jl] + bias[2][i];
        const float go = glds[eb * 33 + 24 + jl] + bias[3][i];
        float c = creg[i];
        const float si = 1.f / (1.f + __expf(-gi));
        const float sf = 1.f / (1.f + __expf(-gf));
        const float so = 1.f / (1.f + __expf(-go));
        const float tg = tanhf(gg);
        c = sf * c + si * tg;
        hres[i] = so * tanhf(c);
        creg[i] = c;
      }

      const uint32_t packed = (uint32_t)f2bf(hres[0]) | ((uint32_t)f2bf(hres[1]) << 16);
      ushort* hdst = (!isL1) ? (p.h0r + (size_t)s * BH)
                             : (p.h1d + (size_t)((s - 1) & 1) * BH);
      uint32_t* hw = (uint32_t*)(hdst + eb * 1024 + jj);
      __hip_atomic_store(hw, packed, __ATOMIC_RELAXED, __HIP_MEMORY_SCOPE_AGENT);
      // Same-address load-back: commitment at the coherence point before arrive.
      uint32_t chk = __hip_atomic_load(hw, __ATOMIC_RELAXED, __HIP_MEMORY_SCOPE_AGENT);
      asm volatile("" :: "v"(chk));

      if (isL1) {
#pragma unroll
        for (int i = 0; i < 2; ++i)
          p.out[(size_t)(s - 1) * BH + eb * 1024 + jj + i] = hres[i];
        if (s - 1 == T_STEPS - 1) {
#pragma unroll
          for (int i = 0; i < 2; ++i) {
            p.out[(size_t)TBH + BH + eb * 1024 + jj + i] = hres[i];
            p.out[(size_t)TBH + 3 * BH + eb * 1024 + jj + i] = creg[i];
          }
        }
      } else if (s == T_STEPS - 1) {
#pragma unroll
        for (int i = 0; i < 2; ++i) {
          p.out[(size_t)TBH + eb * 1024 + jj + i] = hres[i];
          p.out[(size_t)TBH + 2 * BH + eb * 1024 + jj + i] = creg[i];
        }
      }
    }
    gbar(p.bar, s, stripe, isRoot);
  }
}

// ---------------- host ----------------
extern "C" void kernel_launch(void* const* d_in, const int* in_sizes, int n_in,
                              void* d_out, int out_size, void* d_ws, size_t ws_size,
                              hipStream_t stream) {
  const float* x    = (const float*)d_in[0];
  const float* h0   = (const float*)d_in[1];
  const float* c0   = (const float*)d_in[2];
  const float* w_ih = (const float*)d_in[3];
  const float* w_hh = (const float*)d_in[4];
  const float* b_ih = (const float*)d_in[5];
  const float* b_hh = (const float*)d_in[6];
  float* out = (float*)d_out;

  ushort* xb    = (ushort*)d_ws;
  ushort* wihb  = xb + (size_t)TBH;
  ushort* whhb  = wihb + WEL;
  ushort* hinit = whhb + WEL;
  ushort* h0r   = hinit + 2 * (size_t)BH;            // ring: T_STEPS slots
  ushort* h1d   = h0r + (size_t)TBH;
  int*    bar   = (int*)(h1d + 2 * (size_t)BH);

  const size_t need = ((size_t)2 * TBH + 2 * WEL + 4 * (size_t)BH) * 2 + 4096;
  if (ws_size < need) return;  // loud failure: d_out stays poisoned

  { int n = TBH;        k_f32_to_bf16<<<(n / 4 + 255) / 256, 256, 0, stream>>>(x, xb, n); }
  { int n = (int)WEL;   k_f32_to_bf16<<<(n / 4 + 255) / 256, 256, 0, stream>>>(w_ih, wihb, n); }
  { int n = (int)WEL;   k_f32_to_bf16<<<(n / 4 + 255) / 256, 256, 0, stream>>>(w_hh, whhb, n); }
  { int n = 2 * BH;     k_f32_to_bf16<<<(n / 4 + 255) / 256, 256, 0, stream>>>(h0, hinit, n); }
  k_zero<<<2, 256, 0, stream>>>(bar, 512);

  ScanP sp;
  sp.wih = wihb; sp.whh = whhb;
  sp.xb = xb; sp.hinit = hinit;
  sp.h0r = h0r; sp.h1d = h1d;
  sp.c0 = c0; sp.bi = b_ih; sp.bh = b_hh;
  sp.out = out; sp.bar = bar;

  void* kp[1] = {&sp};
  hipLaunchCooperativeKernel(reinterpret_cast<void*>(&k_scan),
                             dim3(NBLK), dim3(256), kp, 0, stream);
}